// Round 7
// baseline (254.173 us; speedup 1.0000x reference)
//
#include <hip/hip_runtime.h>

// NetVLAD fp32, N=64 HW=1024 D=512 K=64. bf16 MFMA.
// R12: drop the 128KB LDS x^T tile (it forced 1 block/CU -> 9% occupancy,
// the measured bottleneck: all pipes <16% busy). After pass A, x is L3-hot
// (134MB < 256MB L3), so pass B re-reads x from global d-major (R7-kvlad
// pattern, 128B coalesced, 256 independent loads/lane). LDS = ab only
// (16KB) -> 2 blocks/CU, 8 waves/CU; block-level A/B phase overlap.
//   kprep:  W[512][64] -> wt[64 k][512 d] bf16; zero a_sum/ssq.
//   kfused: grid 512 = (n, 128px chunk): s=x@W+b (swapped MFMA), lane-local
//           softmax -> ab LDS; barrier; V[512d][64k] += x^T@a; partial out.
//   kpost:  out = sum_8c vpart + a_sum*C; atomic ssq.
//   kscale: intra-norm (per n,k over d) x global L2 (per n), in place.

#define EPSF 1e-12f

typedef short bf16x8 __attribute__((ext_vector_type(8)));
typedef float f32x16 __attribute__((ext_vector_type(16)));

__device__ inline unsigned short f2bf_rne(float f) {
  union { float f; unsigned u; } v; v.f = f;
  unsigned u = v.u;
  unsigned r = u + 0x7fffu + ((u >> 16) & 1u);
  return (unsigned short)(r >> 16);
}
__device__ inline unsigned pk2(float a, float b) {
#if __has_builtin(__builtin_amdgcn_cvt_pk_bf16_f32)
  auto r = __builtin_amdgcn_cvt_pk_bf16_f32(a, b);
  return __builtin_bit_cast(unsigned, r);
#else
  return (unsigned)f2bf_rne(a) | ((unsigned)f2bf_rne(b) << 16);
#endif
}

// ---------------- K0: W transpose (blocks 0-7) + zero stats (block 8) ------
__global__ __launch_bounds__(256) void kprep(
    const float* __restrict__ Wm, unsigned short* __restrict__ wt,
    float* __restrict__ stats /* a_sum(4096) + ssq(4096) */) {
  const int t = threadIdx.x, bx = blockIdx.x;
  if (bx == 8) {
    float4 z = {0.f, 0.f, 0.f, 0.f};
#pragma unroll
    for (int r = 0; r < 8; ++r)
      *(float4*)&stats[(size_t)(r * 256 + t) * 4] = z;
    return;
  }
  __shared__ float tile[64][65];
  {
    int col = (t & 15) * 4, rbase = t >> 4;
#pragma unroll
    for (int r = 0; r < 4; ++r) {
      int row = rbase + 16 * r;
      *(float4*)&tile[row][col] =
          *(const float4*)&Wm[(size_t)(bx * 64 + row) * 64 + col];
    }
  }
  __syncthreads();
  int k = t >> 2, seg = (t & 3) * 16;
  size_t o = (size_t)k * 512 + bx * 64 + seg;
#pragma unroll
  for (int j = 0; j < 16; j += 2)
    *(unsigned*)&wt[o + j] = pk2(tile[seg + j][k], tile[seg + j + 1][k]);
}

// ---------------- fused assign + vlad --------------------------------------
// grid 512 = (n=bid>>3, chunk c=bid&7 of 128 px). 4 waves x 64 lanes.
// LDS: ab[64 k][128 px] bf16, XOR-swizzled = 16KB. 2 blocks/CU.
__global__ __launch_bounds__(256) void kfused(
    const float* __restrict__ x, const unsigned short* __restrict__ wt,
    const float* __restrict__ b, float* __restrict__ vpart,
    float* __restrict__ a_sum) {
  __shared__ unsigned short ab[64 * 128];    // [k][px ^ ((k&15)<<3)]
  const int t = threadIdx.x;
  const int w = t >> 6, lane = t & 63, l31 = lane & 31, h = lane >> 5;
  const int bid = blockIdx.x;
  const int n = bid >> 3, c = bid & 7;
  const unsigned short* w0 = wt + (size_t)l31 * 512;
  const unsigned short* w1 = wt + (size_t)(32 + l31) * 512;
  const int colpx = w * 32 + l31;            // this lane's px column (0..127)

  // ---- pass A: swapped GEMM1 (D[k][px], lane=px) ----
  {
    const float* rowp = x + ((size_t)n * 1024 + c * 128 + colpx) * 512;
    f32x16 s0, s1;
#pragma unroll
    for (int i = 0; i < 16; ++i) { s0[i] = 0.f; s1[i] = 0.f; }
#pragma unroll 8
    for (int st = 0; st < 32; ++st) {
      const int kd = st * 16 + h * 8;
      float4 xa = *(const float4*)&rowp[kd];
      float4 xb = *(const float4*)&rowp[kd + 4];
      union { unsigned u[4]; bf16x8 v; } ax;
      ax.u[0] = pk2(xa.x, xa.y);
      ax.u[1] = pk2(xa.z, xa.w);
      ax.u[2] = pk2(xb.x, xb.y);
      ax.u[3] = pk2(xb.z, xb.w);
      bf16x8 b0 = *(const bf16x8*)&w0[kd];
      bf16x8 b1 = *(const bf16x8*)&w1[kd];
      // SWAPPED: A = W (lane=k-row), B = x (lane=px-col) -> D[k][px]
      s0 = __builtin_amdgcn_mfma_f32_32x32x16_bf16(b0, ax.v, s0, 0, 0, 0);
      s1 = __builtin_amdgcn_mfma_f32_32x32x16_bf16(b1, ax.v, s1, 0, 0, 0);
    }
    // ---- lane-local softmax over k (32 regs here + 32 in h-partner) ----
    float v0[16], v1[16];
    float m = -3.402823466e+38f;
#pragma unroll
    for (int r = 0; r < 16; ++r) {
      const int k0 = (r & 3) + 8 * (r >> 2) + 4 * h;
      v0[r] = s0[r] + b[k0];
      v1[r] = s1[r] + b[k0 + 32];
      m = fmaxf(m, fmaxf(v0[r], v1[r]));
    }
    m = fmaxf(m, __shfl_xor(m, 32, 64));     // combine h-halves (same px)
    float a0[16], a1[16];
    float S = 0.f;
#pragma unroll
    for (int r = 0; r < 16; ++r) {
      a0[r] = __expf(v0[r] - m);
      a1[r] = __expf(v1[r] - m);
      S += a0[r] + a1[r];
    }
    S += __shfl_xor(S, 32, 64);
    const float inv = 1.0f / S;
#pragma unroll
    for (int r = 0; r < 16; ++r) {
      a0[r] *= inv; a1[r] *= inv;
      const int k0 = (r & 3) + 8 * (r >> 2) + 4 * h, k1 = k0 + 32;
      ab[k0 * 128 + (colpx ^ ((k0 & 15) << 3))] = f2bf_rne(a0[r]);
      ab[k1 * 128 + (colpx ^ ((k1 & 15) << 3))] = f2bf_rne(a1[r]);
    }
    // ---- a_sum: ILP-16 butterfly over 32 px-lanes (per h-half) ----
#pragma unroll
    for (int msk = 1; msk < 32; msk <<= 1) {
#pragma unroll
      for (int r = 0; r < 16; ++r) {
        a0[r] += __shfl_xor(a0[r], msk, 64);
        a1[r] += __shfl_xor(a1[r], msk, 64);
      }
    }
    if (l31 < 16) {
      const int r = l31;
      const int k0 = (r & 3) + 8 * (r >> 2) + 4 * h;
      atomicAdd(&a_sum[n * 64 + k0], a0[r]);
      atomicAdd(&a_sum[n * 64 + k0 + 32], a1[r]);
    }
  }
  __syncthreads();

  // ---- pass B: V[512d][64k] += x^T @ a; x from global (L3-hot) ----
  const int dw = w * 128;
  f32x16 accv[8];                            // [dt 0..3][kt 0..1]
#pragma unroll
  for (int i = 0; i < 8; ++i)
#pragma unroll
    for (int j = 0; j < 16; ++j) accv[i][j] = 0.f;

  const float* xg = x + ((size_t)n * 1024 + c * 128) * 512;
#pragma unroll 2
  for (int m = 0; m < 8; ++m) {
    const int px0 = m * 16 + h * 8;
    bf16x8 bb0 = *(const bf16x8*)&ab[l31 * 128 + (px0 ^ ((l31 & 15) << 3))];
    bf16x8 bb1 =
        *(const bf16x8*)&ab[(32 + l31) * 128 + (px0 ^ ((l31 & 15) << 3))];
#pragma unroll
    for (int dt = 0; dt < 4; ++dt) {
      const int d = dw + dt * 32 + l31;
      const float* xp = xg + (size_t)px0 * 512 + d;
      float a[8];
#pragma unroll
      for (int j = 0; j < 8; ++j) a[j] = xp[(size_t)j * 512];
      union { unsigned u[4]; bf16x8 v; } aa;
      aa.u[0] = pk2(a[0], a[1]);
      aa.u[1] = pk2(a[2], a[3]);
      aa.u[2] = pk2(a[4], a[5]);
      aa.u[3] = pk2(a[6], a[7]);
      accv[dt * 2 + 0] =
          __builtin_amdgcn_mfma_f32_32x32x16_bf16(aa.v, bb0, accv[dt * 2 + 0], 0, 0, 0);
      accv[dt * 2 + 1] =
          __builtin_amdgcn_mfma_f32_32x32x16_bf16(aa.v, bb1, accv[dt * 2 + 1], 0, 0, 0);
    }
  }

  // epilogue: plain-write this chunk's partial V [512][64]
  float* vp = vpart + (size_t)c * 2097152 + (size_t)n * 32768;
#pragma unroll
  for (int dt = 0; dt < 4; ++dt) {
#pragma unroll
    for (int kt = 0; kt < 2; ++kt) {
      const f32x16 a = accv[dt * 2 + kt];
      const int kcol = kt * 32 + l31;
#pragma unroll
      for (int r = 0; r < 16; ++r) {
        const int drow = dw + dt * 32 + (r & 3) + 8 * (r >> 2) + 4 * h;
        vp[drow * 64 + kcol] = a[r];
      }
    }
  }
}

// ---------------- kpost: out = sum_c vpart + a_sum*C; atomic ssq -----------
__global__ __launch_bounds__(256) void kpost(
    const float* __restrict__ vpart, const float* __restrict__ a_sum,
    const float* __restrict__ C, float* __restrict__ out,
    float* __restrict__ ssq) {
  const int bid = blockIdx.x;               // 512: n fast for locality
  const int n = bid & 63, d0 = (bid >> 6) * 64;
  const int t = threadIdx.x, k = t & 63, dr = t >> 6;
  const float as = a_sum[n * 64 + k];
  const size_t nb = (size_t)n * 32768;
  float sq = 0.f;
#pragma unroll
  for (int r = 0; r < 16; ++r) {
    const int d = d0 + dr * 16 + r;
    const size_t idx = nb + (size_t)d * 64 + k;
    float o = as * C[(size_t)d * 64 + k];
#pragma unroll
    for (int cc = 0; cc < 8; ++cc) o += vpart[idx + (size_t)cc * 2097152];
    out[idx] = o;
    sq += o * o;
  }
  atomicAdd(&ssq[n * 64 + k], sq);
}

// ---------------- kscale: normalize in place -------------------------------
__global__ __launch_bounds__(256) void kscale(
    float* __restrict__ out, const float* __restrict__ ssq) {
  const int n = blockIdx.y, slice = blockIdx.x;
  const int t = threadIdx.x, k = t & 63, rg = t >> 6;
  __shared__ float sk[64];
  __shared__ float tot;
  if (t < 64) {
    float cc = ssq[n * 64 + t];
    sk[t] = rsqrtf(cc + EPSF);
    float contrib = cc / (cc + EPSF);
#pragma unroll
    for (int m = 32; m; m >>= 1) contrib += __shfl_xor(contrib, m, 64);
    if (t == 0) tot = rsqrtf(contrib + EPSF);
  }
  __syncthreads();
  const float scale = sk[k] * tot;
  float* vb = out + (size_t)n * 32768 + (size_t)slice * 4096;
#pragma unroll
  for (int r = rg; r < 64; r += 4) vb[r * 64 + k] *= scale;
}

extern "C" void kernel_launch(void* const* d_in, const int* in_sizes, int n_in,
                              void* d_out, int out_size, void* d_ws, size_t ws_size,
                              hipStream_t stream) {
  const float* x  = (const float*)d_in[0];   // [64,32,32,512]
  const float* Wm = (const float*)d_in[1];   // [512,64]
  const float* b  = (const float*)d_in[2];   // [64]
  const float* C  = (const float*)d_in[3];   // [512,64]
  float* out = (float*)d_out;                // [64, 32768]

  float* vpart = (float*)d_ws;                         // 64 MiB: 8 x [64][512][64]
  unsigned short* wt = (unsigned short*)(vpart + (size_t)8 * 2097152);  // 64 KiB
  float* stats = (float*)(wt + (size_t)64 * 512);      // a_sum 4096 + ssq 4096
  float* a_sum = stats;
  float* ssq   = stats + 4096;

  kprep<<<dim3(9), dim3(256), 0, stream>>>(Wm, wt, stats);
  kfused<<<dim3(512), dim3(256), 0, stream>>>(x, wt, b, vpart, a_sum);
  kpost<<<dim3(512), dim3(256), 0, stream>>>(vpart, a_sum, C, out, ssq);
  kscale<<<dim3(8, 64), dim3(256), 0, stream>>>(out, ssq);
}